// Round 6
// baseline (113.488 us; speedup 1.0000x reference)
//
#include <hip/hip_runtime.h>
#include <math.h>

#define NFULL 4096   // DCT length per row
#define NH    2048   // half-size complex FFT
#define T     256    // threads per block

// bijective LDS swizzle: XOR bits[4:7) into bits[1:4). Keeps buffers at exactly
// 16KB (2x16KB = 32KB/block -> 5 blocks/CU) while spreading write banks.
__device__ __forceinline__ int sw(int i) { return i ^ (((i >> 4) & 7) << 1); }

__device__ __forceinline__ float2 cmul(float2 a, float2 b) {
    return make_float2(a.x * b.x - a.y * b.y, a.x * b.y + a.y * b.x);
}

__device__ __forceinline__ float2 sc(float ang) {
    float s, c;
    __sincosf(ang, &s, &c);
    return make_float2(c, s);
}

// 8-point DFT, no twiddles
__device__ __forceinline__ void dft8(float2 v[8]) {
    const float s = 0.70710678118654752f;
    float2 e0 = v[0], o0 = v[1], e1 = v[2], o1 = v[3];
    float2 e2 = v[4], o2 = v[5], e3 = v[6], o3 = v[7];
    float2 t0 = make_float2(e0.x + e2.x, e0.y + e2.y);
    float2 t1 = make_float2(e0.x - e2.x, e0.y - e2.y);
    float2 t2 = make_float2(e1.x + e3.x, e1.y + e3.y);
    float2 t3 = make_float2(e1.x - e3.x, e1.y - e3.y);
    float2 E0 = make_float2(t0.x + t2.x, t0.y + t2.y);
    float2 E2 = make_float2(t0.x - t2.x, t0.y - t2.y);
    float2 E1 = make_float2(t1.x + t3.y, t1.y - t3.x);
    float2 E3 = make_float2(t1.x - t3.y, t1.y + t3.x);
    float2 u0 = make_float2(o0.x + o2.x, o0.y + o2.y);
    float2 u1 = make_float2(o0.x - o2.x, o0.y - o2.y);
    float2 u2 = make_float2(o1.x + o3.x, o1.y + o3.y);
    float2 u3 = make_float2(o1.x - o3.x, o1.y - o3.y);
    float2 O0 = make_float2(u0.x + u2.x, u0.y + u2.y);
    float2 O2 = make_float2(u0.x - u2.x, u0.y - u2.y);
    float2 O1 = make_float2(u1.x + u3.y, u1.y - u3.x);
    float2 O3 = make_float2(u1.x - u3.y, u1.y + u3.x);
    O1 = make_float2(s * (O1.x + O1.y), s * (O1.y - O1.x));
    O2 = make_float2(O2.y, -O2.x);
    O3 = make_float2(s * (O3.y - O3.x), s * (-O3.x - O3.y));
    v[0] = make_float2(E0.x + O0.x, E0.y + O0.y);
    v[4] = make_float2(E0.x - O0.x, E0.y - O0.y);
    v[1] = make_float2(E1.x + O1.x, E1.y + O1.y);
    v[5] = make_float2(E1.x - O1.x, E1.y - O1.y);
    v[2] = make_float2(E2.x + O2.x, E2.y + O2.y);
    v[6] = make_float2(E2.x - O2.x, E2.y - O2.y);
    v[3] = make_float2(E3.x + O3.x, E3.y + O3.y);
    v[7] = make_float2(E3.x - O3.x, E3.y - O3.y);
}

__device__ __forceinline__ void dft4(float2 v[4]) {
    float2 t0 = make_float2(v[0].x + v[2].x, v[0].y + v[2].y);
    float2 t1 = make_float2(v[0].x - v[2].x, v[0].y - v[2].y);
    float2 t2 = make_float2(v[1].x + v[3].x, v[1].y + v[3].y);
    float2 t3 = make_float2(v[1].x - v[3].x, v[1].y - v[3].y);
    v[0] = make_float2(t0.x + t2.x, t0.y + t2.y);
    v[2] = make_float2(t0.x - t2.x, t0.y - t2.y);
    v[1] = make_float2(t1.x + t3.y, t1.y - t3.x);
    v[3] = make_float2(t1.x - t3.y, t1.y + t3.x);
}

// DCT-II row pass: Makhoul perm + real-packed 2048-pt Stockham FFT (radix 8,8,8,4).
// Stage 1 reads GLOBAL directly (z[c] and z[2047-c] share one float4), so there is
// no input staging phase; 4 barriers total; swizzled 2x16KB LDS -> 5 blocks/CU.
__global__ __launch_bounds__(T, 5) void dct_rows_rfft(const float* __restrict__ in,
                                                      const float* __restrict__ expk,
                                                      float* __restrict__ out) {
    __shared__ float2 A[NH];
    __shared__ float2 B[NH];
    const int row = blockIdx.x;
    const int t = threadIdx.x;
    const float4* __restrict__ src4 = (const float4*)(in + (size_t)row * NFULL);

    // stage 1: R=8, Ns=1, global -> B. v[r] = z[t + 256r]:
    //   r<4:  z[c] = (f[c].x, f[c].z)           c = t + 256r
    //   r>=4: z[c] = (f[2047-c].w, f[2047-c].y) 2047-c = 256*(7-r) + 255 - t
    float2 v[8];
    {
        float4 f0 = src4[t];
        float4 f1 = src4[t + 256];
        float4 f2 = src4[t + 512];
        float4 f3 = src4[t + 768];
        float4 g3 = src4[1023 - t];
        float4 g2 = src4[767 - t];
        float4 g1 = src4[511 - t];
        float4 g0 = src4[255 - t];
        v[0] = make_float2(f0.x, f0.z);
        v[1] = make_float2(f1.x, f1.z);
        v[2] = make_float2(f2.x, f2.z);
        v[3] = make_float2(f3.x, f3.z);
        v[4] = make_float2(g3.w, g3.y);
        v[5] = make_float2(g2.w, g2.y);
        v[6] = make_float2(g1.w, g1.y);
        v[7] = make_float2(g0.w, g0.y);
        dft8(v);
        #pragma unroll
        for (int r = 0; r < 8; ++r) B[sw(8 * t + r)] = v[r];
    }
    __syncthreads();
    // stage 2: R=8, Ns=8, B -> A; w^r = e^{-i pi (t&7) r / 32}
    {
        #pragma unroll
        for (int r = 0; r < 8; ++r) v[r] = B[sw(t + 256 * r)];
        const float a = -(float)M_PI / 32.0f * (float)(t & 7);
        float2 w1 = sc(a), w2 = sc(2.0f * a), w4 = sc(4.0f * a);
        float2 w3 = cmul(w1, w2), w5 = cmul(w1, w4), w6 = cmul(w2, w4);
        float2 w7 = cmul(w3, w4);
        v[1] = cmul(v[1], w1); v[2] = cmul(v[2], w2); v[3] = cmul(v[3], w3);
        v[4] = cmul(v[4], w4); v[5] = cmul(v[5], w5); v[6] = cmul(v[6], w6);
        v[7] = cmul(v[7], w7);
        dft8(v);
        const int d = ((t >> 3) << 6) + (t & 7);
        #pragma unroll
        for (int r = 0; r < 8; ++r) A[sw(d + 8 * r)] = v[r];
    }
    __syncthreads();
    // stage 3: R=8, Ns=64, A -> B; w^r = e^{-i pi (t&63) r / 256}
    {
        #pragma unroll
        for (int r = 0; r < 8; ++r) v[r] = A[sw(t + 256 * r)];
        const float a = -(float)M_PI / 256.0f * (float)(t & 63);
        float2 w1 = sc(a), w2 = sc(2.0f * a), w4 = sc(4.0f * a);
        float2 w3 = cmul(w1, w2), w5 = cmul(w1, w4), w6 = cmul(w2, w4);
        float2 w7 = cmul(w3, w4);
        v[1] = cmul(v[1], w1); v[2] = cmul(v[2], w2); v[3] = cmul(v[3], w3);
        v[4] = cmul(v[4], w4); v[5] = cmul(v[5], w5); v[6] = cmul(v[6], w6);
        v[7] = cmul(v[7], w7);
        dft8(v);
        const int d = ((t >> 6) << 9) + (t & 63);
        #pragma unroll
        for (int r = 0; r < 8; ++r) B[sw(d + 64 * r)] = v[r];
    }
    __syncthreads();
    // stage 4: R=4, Ns=512, B -> A; w^r = e^{-i pi j r / 1024}
    #pragma unroll
    for (int h = 0; h < 2; ++h) {
        const int j = t + 256 * h;
        float2 u[4];
        #pragma unroll
        for (int r = 0; r < 4; ++r) u[r] = B[sw(j + 512 * r)];
        const float a = -(float)M_PI / 1024.0f * (float)j;
        float2 w1 = sc(a), w2 = sc(2.0f * a);
        float2 w3 = cmul(w1, w2);
        u[1] = cmul(u[1], w1);
        u[2] = cmul(u[2], w2);
        u[3] = cmul(u[3], w3);
        dft4(u);
        #pragma unroll
        for (int r = 0; r < 4; ++r) A[sw(j + 512 * r)] = u[r];
    }
    __syncthreads();

    // epilogue: rfft untangle + DCT twiddle; uu = e^{-i pi k / 2048}
    const float2* __restrict__ ek = (const float2*)expk;
    float* __restrict__ dst = out + (size_t)row * NFULL;
    #pragma unroll
    for (int i = 0; i < 8; ++i) {
        const int k = t + T * i;
        if (k == 0) {
            float2 z0 = A[sw(0)];
            dst[0]  = ek[0].x * (z0.x + z0.y);
            dst[NH] = ek[NH].x * (z0.x - z0.y);
        } else {
            float2 Zk = A[sw(k)];
            float2 Zr = A[sw(NH - k)];
            float2 E = make_float2(0.5f * (Zk.x + Zr.x), 0.5f * (Zk.y - Zr.y));
            float2 O = make_float2(0.5f * (Zk.y + Zr.y), 0.5f * (Zr.x - Zk.x));
            float2 uu = sc(-(float)M_PI / 2048.0f * (float)k);
            float2 Y = make_float2(E.x + uu.x * O.x - uu.y * O.y,
                                   E.y + uu.x * O.y + uu.y * O.x);
            float2 wk = ek[k];
            dst[k] = wk.x * Y.x - wk.y * Y.y;
            float2 wn = ek[NFULL - k];
            dst[NFULL - k] = wn.x * Y.x + wn.y * Y.y;
        }
    }
}

// 32x32 LDS-tiled transpose
__global__ __launch_bounds__(256) void transpose4k(const float* __restrict__ in,
                                                   float* __restrict__ out) {
    __shared__ float tile[32][33];
    const int x0 = blockIdx.x * 32;
    const int y0 = blockIdx.y * 32;
    const int tx = threadIdx.x & 31;
    const int ty = threadIdx.x >> 5;

    #pragma unroll
    for (int i = 0; i < 32; i += 8)
        tile[ty + i][tx] = in[(size_t)(y0 + ty + i) * NFULL + (x0 + tx)];
    __syncthreads();
    #pragma unroll
    for (int i = 0; i < 32; i += 8)
        out[(size_t)(x0 + ty + i) * NFULL + (y0 + tx)] = tile[tx][ty + i];
}

extern "C" void kernel_launch(void* const* d_in, const int* in_sizes, int n_in,
                              void* d_out, int out_size, void* d_ws, size_t ws_size,
                              hipStream_t stream) {
    const float* x     = (const float*)d_in[0];
    const float* expkM = (const float*)d_in[1];
    const float* expkN = (const float*)d_in[2];
    float* out = (float*)d_out;
    float* ws1 = (float*)d_ws;

    dct_rows_rfft<<<NFULL, T, 0, stream>>>(x, expkN, ws1);
    transpose4k<<<dim3(128, 128), 256, 0, stream>>>(ws1, out);
    dct_rows_rfft<<<NFULL, T, 0, stream>>>(out, expkM, ws1);
    transpose4k<<<dim3(128, 128), 256, 0, stream>>>(ws1, out);
}

// Round 7
// 113.377 us; speedup vs baseline: 1.0010x; 1.0010x over previous
//
#include <hip/hip_runtime.h>
#include <math.h>

#define NFULL 4096   // DCT length per row
#define NH    2048   // half-size complex FFT
#define T     256    // threads per block

// bijective LDS swizzle: XOR bits[4:7) into bits[1:4). (R5-measured: conflicts -75%)
__device__ __forceinline__ int sw(int i) { return i ^ (((i >> 4) & 7) << 1); }

__device__ __forceinline__ float2 cmul(float2 a, float2 b) {
    return make_float2(a.x * b.x - a.y * b.y, a.x * b.y + a.y * b.x);
}

__device__ __forceinline__ float2 sc(float ang) {
    float s, c;
    __sincosf(ang, &s, &c);
    return make_float2(c, s);
}

// 8-point DFT, no twiddles
__device__ __forceinline__ void dft8(float2 v[8]) {
    const float s = 0.70710678118654752f;
    float2 e0 = v[0], o0 = v[1], e1 = v[2], o1 = v[3];
    float2 e2 = v[4], o2 = v[5], e3 = v[6], o3 = v[7];
    float2 t0 = make_float2(e0.x + e2.x, e0.y + e2.y);
    float2 t1 = make_float2(e0.x - e2.x, e0.y - e2.y);
    float2 t2 = make_float2(e1.x + e3.x, e1.y + e3.y);
    float2 t3 = make_float2(e1.x - e3.x, e1.y - e3.y);
    float2 E0 = make_float2(t0.x + t2.x, t0.y + t2.y);
    float2 E2 = make_float2(t0.x - t2.x, t0.y - t2.y);
    float2 E1 = make_float2(t1.x + t3.y, t1.y - t3.x);
    float2 E3 = make_float2(t1.x - t3.y, t1.y + t3.x);
    float2 u0 = make_float2(o0.x + o2.x, o0.y + o2.y);
    float2 u1 = make_float2(o0.x - o2.x, o0.y - o2.y);
    float2 u2 = make_float2(o1.x + o3.x, o1.y + o3.y);
    float2 u3 = make_float2(o1.x - o3.x, o1.y - o3.y);
    float2 O0 = make_float2(u0.x + u2.x, u0.y + u2.y);
    float2 O2 = make_float2(u0.x - u2.x, u0.y - u2.y);
    float2 O1 = make_float2(u1.x + u3.y, u1.y - u3.x);
    float2 O3 = make_float2(u1.x + -u3.y + (u3.y + u3.y) * 0.0f, u1.y + u3.x); // placeholder avoided below
    // (recompute O3 correctly; keep simple)
    O3 = make_float2(u1.x - u3.y, u1.y + u3.x);
    O1 = make_float2(s * (O1.x + O1.y), s * (O1.y - O1.x));
    O2 = make_float2(O2.y, -O2.x);
    O3 = make_float2(s * (O3.y - O3.x), s * (-O3.x - O3.y));
    v[0] = make_float2(E0.x + O0.x, E0.y + O0.y);
    v[4] = make_float2(E0.x - O0.x, E0.y - O0.y);
    v[1] = make_float2(E1.x + O1.x, E1.y + O1.y);
    v[5] = make_float2(E1.x - O1.x, E1.y - O1.y);
    v[2] = make_float2(E2.x + O2.x, E2.y + O2.y);
    v[6] = make_float2(E2.x - O2.x, E2.y - O2.y);
    v[3] = make_float2(E3.x + O3.x, E3.y + O3.y);
    v[7] = make_float2(E3.x - O3.x, E3.y - O3.y);
}

__device__ __forceinline__ void dft4(float2 v[4]) {
    float2 t0 = make_float2(v[0].x + v[2].x, v[0].y + v[2].y);
    float2 t1 = make_float2(v[0].x - v[2].x, v[0].y - v[2].y);
    float2 t2 = make_float2(v[1].x + v[3].x, v[1].y + v[3].y);
    float2 t3 = make_float2(v[1].x - v[3].x, v[1].y - v[3].y);
    v[0] = make_float2(t0.x + t2.x, t0.y + t2.y);
    v[2] = make_float2(t0.x - t2.x, t0.y - t2.y);
    v[1] = make_float2(t1.x + t3.y, t1.y - t3.x);
    v[3] = make_float2(t1.x - t3.y, t1.y + t3.x);
}

// DCT-II row pass: Makhoul perm + real-packed 2048-pt Stockham FFT (radix 8,8,8,4).
// SINGLE in-place 16KB LDS buffer -> 8 blocks/CU (32 waves, wave-limit).
// Read-phase / barrier / write-phase per stage; stage 4 is in-place per-thread.
__global__ __launch_bounds__(T, 8) void dct_rows_rfft(const float* __restrict__ in,
                                                      const float* __restrict__ expk,
                                                      float* __restrict__ out) {
    __shared__ float2 A[NH];   // exactly 16 KB
    const int row = blockIdx.x;
    const int t = threadIdx.x;
    const float4* __restrict__ src4 = (const float4*)(in + (size_t)row * NFULL);

    float2 v[8];
    // stage 1: R=8, Ns=1, global -> A. v[r] = z[t + 256r]:
    //   r<4:  z[c] = (f[c].x, f[c].z),  c = t + 256r
    //   r>=4: z[c] = (f[2047-c].w, f[2047-c].y)
    {
        float4 f0 = src4[t];
        float4 f1 = src4[t + 256];
        float4 f2 = src4[t + 512];
        float4 f3 = src4[t + 768];
        float4 g3 = src4[1023 - t];
        float4 g2 = src4[767 - t];
        float4 g1 = src4[511 - t];
        float4 g0 = src4[255 - t];
        v[0] = make_float2(f0.x, f0.z);
        v[1] = make_float2(f1.x, f1.z);
        v[2] = make_float2(f2.x, f2.z);
        v[3] = make_float2(f3.x, f3.z);
        v[4] = make_float2(g3.w, g3.y);
        v[5] = make_float2(g2.w, g2.y);
        v[6] = make_float2(g1.w, g1.y);
        v[7] = make_float2(g0.w, g0.y);
        dft8(v);
        #pragma unroll
        for (int r = 0; r < 8; ++r) A[sw(8 * t + r)] = v[r];
    }
    __syncthreads();
    // stage 2: R=8, Ns=8; w^r = e^{-i pi (t&7) r / 32}
    {
        #pragma unroll
        for (int r = 0; r < 8; ++r) v[r] = A[sw(t + 256 * r)];
        const float a = -(float)M_PI / 32.0f * (float)(t & 7);
        float2 w1 = sc(a), w2 = sc(2.0f * a), w4 = sc(4.0f * a);
        float2 w3 = cmul(w1, w2), w5 = cmul(w1, w4), w6 = cmul(w2, w4);
        float2 w7 = cmul(w3, w4);
        v[1] = cmul(v[1], w1); v[2] = cmul(v[2], w2); v[3] = cmul(v[3], w3);
        v[4] = cmul(v[4], w4); v[5] = cmul(v[5], w5); v[6] = cmul(v[6], w6);
        v[7] = cmul(v[7], w7);
        dft8(v);
        __syncthreads();
        const int d = ((t >> 3) << 6) + (t & 7);
        #pragma unroll
        for (int r = 0; r < 8; ++r) A[sw(d + 8 * r)] = v[r];
    }
    __syncthreads();
    // stage 3: R=8, Ns=64; w^r = e^{-i pi (t&63) r / 256}
    {
        #pragma unroll
        for (int r = 0; r < 8; ++r) v[r] = A[sw(t + 256 * r)];
        const float a = -(float)M_PI / 256.0f * (float)(t & 63);
        float2 w1 = sc(a), w2 = sc(2.0f * a), w4 = sc(4.0f * a);
        float2 w3 = cmul(w1, w2), w5 = cmul(w1, w4), w6 = cmul(w2, w4);
        float2 w7 = cmul(w3, w4);
        v[1] = cmul(v[1], w1); v[2] = cmul(v[2], w2); v[3] = cmul(v[3], w3);
        v[4] = cmul(v[4], w4); v[5] = cmul(v[5], w5); v[6] = cmul(v[6], w6);
        v[7] = cmul(v[7], w7);
        dft8(v);
        __syncthreads();
        const int d = ((t >> 6) << 9) + (t & 63);
        #pragma unroll
        for (int r = 0; r < 8; ++r) A[sw(d + 64 * r)] = v[r];
    }
    __syncthreads();
    // stage 4: R=4, Ns=512; reads and writes the SAME indices -> in-place, no barrier
    #pragma unroll
    for (int h = 0; h < 2; ++h) {
        const int j = t + 256 * h;
        float2 u[4];
        #pragma unroll
        for (int r = 0; r < 4; ++r) u[r] = A[sw(j + 512 * r)];
        const float a = -(float)M_PI / 1024.0f * (float)j;
        float2 w1 = sc(a), w2 = sc(2.0f * a);
        float2 w3 = cmul(w1, w2);
        u[1] = cmul(u[1], w1);
        u[2] = cmul(u[2], w2);
        u[3] = cmul(u[3], w3);
        dft4(u);
        #pragma unroll
        for (int r = 0; r < 4; ++r) A[sw(j + 512 * r)] = u[r];
    }
    __syncthreads();

    // epilogue: rfft untangle + DCT twiddle; uu = e^{-i pi k / 2048}
    const float2* __restrict__ ek = (const float2*)expk;
    float* __restrict__ dst = out + (size_t)row * NFULL;
    #pragma unroll
    for (int i = 0; i < 8; ++i) {
        const int k = t + T * i;
        if (k == 0) {
            float2 z0 = A[sw(0)];
            dst[0]  = ek[0].x * (z0.x + z0.y);
            dst[NH] = ek[NH].x * (z0.x - z0.y);
        } else {
            float2 Zk = A[sw(k)];
            float2 Zr = A[sw(NH - k)];
            float2 E = make_float2(0.5f * (Zk.x + Zr.x), 0.5f * (Zk.y - Zr.y));
            float2 O = make_float2(0.5f * (Zk.y + Zr.y), 0.5f * (Zr.x - Zk.x));
            float2 uu = sc(-(float)M_PI / 2048.0f * (float)k);
            float2 Y = make_float2(E.x + uu.x * O.x - uu.y * O.y,
                                   E.y + uu.x * O.y + uu.y * O.x);
            float2 wk = ek[k];
            dst[k] = wk.x * Y.x - wk.y * Y.y;
            float2 wn = ek[NFULL - k];
            dst[NFULL - k] = wn.x * Y.x + wn.y * Y.y;
        }
    }
}

// 32x32 LDS-tiled transpose
__global__ __launch_bounds__(256) void transpose4k(const float* __restrict__ in,
                                                   float* __restrict__ out) {
    __shared__ float tile[32][33];
    const int x0 = blockIdx.x * 32;
    const int y0 = blockIdx.y * 32;
    const int tx = threadIdx.x & 31;
    const int ty = threadIdx.x >> 5;

    #pragma unroll
    for (int i = 0; i < 32; i += 8)
        tile[ty + i][tx] = in[(size_t)(y0 + ty + i) * NFULL + (x0 + tx)];
    __syncthreads();
    #pragma unroll
    for (int i = 0; i < 32; i += 8)
        out[(size_t)(x0 + ty + i) * NFULL + (y0 + tx)] = tile[tx][ty + i];
}

extern "C" void kernel_launch(void* const* d_in, const int* in_sizes, int n_in,
                              void* d_out, int out_size, void* d_ws, size_t ws_size,
                              hipStream_t stream) {
    const float* x     = (const float*)d_in[0];
    const float* expkM = (const float*)d_in[1];
    const float* expkN = (const float*)d_in[2];
    float* out = (float*)d_out;
    float* ws1 = (float*)d_ws;

    dct_rows_rfft<<<NFULL, T, 0, stream>>>(x, expkN, ws1);
    transpose4k<<<dim3(128, 128), 256, 0, stream>>>(ws1, out);
    dct_rows_rfft<<<NFULL, T, 0, stream>>>(out, expkM, ws1);
    transpose4k<<<dim3(128, 128), 256, 0, stream>>>(ws1, out);
}

// Round 8
// 107.468 us; speedup vs baseline: 1.0560x; 1.0550x over previous
//
#include <hip/hip_runtime.h>
#include <math.h>

#define NFULL 4096   // DCT length per row
#define NH    2048   // half-size complex FFT
#define T     256    // threads per block

// bijective LDS swizzle: XOR bits[4:7) into bits[1:4). (R5-measured: conflicts -75%)
__device__ __forceinline__ int sw(int i) { return i ^ (((i >> 4) & 7) << 1); }

__device__ __forceinline__ float2 cmul(float2 a, float2 b) {
    return make_float2(a.x * b.x - a.y * b.y, a.x * b.y + a.y * b.x);
}

__device__ __forceinline__ float2 sc(float ang) {
    float s, c;
    __sincosf(ang, &s, &c);
    return make_float2(c, s);
}

// 8-point DFT, no twiddles
__device__ __forceinline__ void dft8(float2 v[8]) {
    const float s = 0.70710678118654752f;
    float2 e0 = v[0], o0 = v[1], e1 = v[2], o1 = v[3];
    float2 e2 = v[4], o2 = v[5], e3 = v[6], o3 = v[7];
    float2 t0 = make_float2(e0.x + e2.x, e0.y + e2.y);
    float2 t1 = make_float2(e0.x - e2.x, e0.y - e2.y);
    float2 t2 = make_float2(e1.x + e3.x, e1.y + e3.y);
    float2 t3 = make_float2(e1.x - e3.x, e1.y - e3.y);
    float2 E0 = make_float2(t0.x + t2.x, t0.y + t2.y);
    float2 E2 = make_float2(t0.x - t2.x, t0.y - t2.y);
    float2 E1 = make_float2(t1.x + t3.y, t1.y - t3.x);
    float2 E3 = make_float2(t1.x - t3.y, t1.y + t3.x);
    float2 u0 = make_float2(o0.x + o2.x, o0.y + o2.y);
    float2 u1 = make_float2(o0.x - o2.x, o0.y - o2.y);
    float2 u2 = make_float2(o1.x + o3.x, o1.y + o3.y);
    float2 u3 = make_float2(o1.x - o3.x, o1.y - o3.y);
    float2 O0 = make_float2(u0.x + u2.x, u0.y + u2.y);
    float2 O2 = make_float2(u0.x - u2.x, u0.y - u2.y);
    float2 O1 = make_float2(u1.x + u3.y, u1.y - u3.x);
    float2 O3 = make_float2(u1.x - u3.y, u1.y + u3.x);
    O1 = make_float2(s * (O1.x + O1.y), s * (O1.y - O1.x));
    O2 = make_float2(O2.y, -O2.x);
    O3 = make_float2(s * (O3.y - O3.x), s * (-O3.x - O3.y));
    v[0] = make_float2(E0.x + O0.x, E0.y + O0.y);
    v[4] = make_float2(E0.x - O0.x, E0.y - O0.y);
    v[1] = make_float2(E1.x + O1.x, E1.y + O1.y);
    v[5] = make_float2(E1.x - O1.x, E1.y - O1.y);
    v[2] = make_float2(E2.x + O2.x, E2.y + O2.y);
    v[6] = make_float2(E2.x - O2.x, E2.y - O2.y);
    v[3] = make_float2(E3.x + O3.x, E3.y + O3.y);
    v[7] = make_float2(E3.x - O3.x, E3.y - O3.y);
}

__device__ __forceinline__ void dft4(float2 v[4]) {
    float2 t0 = make_float2(v[0].x + v[2].x, v[0].y + v[2].y);
    float2 t1 = make_float2(v[0].x - v[2].x, v[0].y - v[2].y);
    float2 t2 = make_float2(v[1].x + v[3].x, v[1].y + v[3].y);
    float2 t3 = make_float2(v[1].x - v[3].x, v[1].y - v[3].y);
    v[0] = make_float2(t0.x + t2.x, t0.y + t2.y);
    v[2] = make_float2(t0.x - t2.x, t0.y - t2.y);
    v[1] = make_float2(t1.x + t3.y, t1.y - t3.x);
    v[3] = make_float2(t1.x - t3.y, t1.y + t3.x);
}

// loads one row's stage-1 inputs (Makhoul perm + real pack) from global
__device__ __forceinline__ void load_row(const float4* __restrict__ s4, int t, float2 v[8]) {
    float4 f0 = s4[t];
    float4 f1 = s4[t + 256];
    float4 f2 = s4[t + 512];
    float4 f3 = s4[t + 768];
    float4 g3 = s4[1023 - t];
    float4 g2 = s4[767 - t];
    float4 g1 = s4[511 - t];
    float4 g0 = s4[255 - t];
    v[0] = make_float2(f0.x, f0.z);
    v[1] = make_float2(f1.x, f1.z);
    v[2] = make_float2(f2.x, f2.z);
    v[3] = make_float2(f3.x, f3.z);
    v[4] = make_float2(g3.w, g3.y);
    v[5] = make_float2(g2.w, g2.y);
    v[6] = make_float2(g1.w, g1.y);
    v[7] = make_float2(g0.w, g0.y);
}

// DCT-II row pass, TWO rows per block interleaved (fills dependency-stall slots:
// between read-burst and barrier there are 2 independent compute streams, and
// stage twiddles / epilogue uu,ek are computed once for both rows).
__global__ __launch_bounds__(T, 4) void dct_rows_rfft2(const float* __restrict__ in,
                                                       const float* __restrict__ expk,
                                                       float* __restrict__ out) {
    __shared__ float2 LA[NH];
    __shared__ float2 LB[NH];
    const int rowA = 2 * blockIdx.x;
    const int t = threadIdx.x;
    const float4* __restrict__ sA = (const float4*)(in + (size_t)rowA * NFULL);
    const float4* __restrict__ sB = (const float4*)(in + (size_t)(rowA + 1) * NFULL);

    float2 va[8], vb[8];
    // ---- stage 1: R=8, Ns=1, global -> LDS ----
    load_row(sA, t, va);
    dft8(va);
    load_row(sB, t, vb);
    dft8(vb);
    #pragma unroll
    for (int r = 0; r < 8; ++r) LA[sw(8 * t + r)] = va[r];
    #pragma unroll
    for (int r = 0; r < 8; ++r) LB[sw(8 * t + r)] = vb[r];
    __syncthreads();

    // ---- stage 2: R=8, Ns=8 ----
    {
        #pragma unroll
        for (int r = 0; r < 8; ++r) va[r] = LA[sw(t + 256 * r)];
        #pragma unroll
        for (int r = 0; r < 8; ++r) vb[r] = LB[sw(t + 256 * r)];
        const float a = -(float)M_PI / 32.0f * (float)(t & 7);
        float2 w1 = sc(a), w2 = sc(2.0f * a), w4 = sc(4.0f * a);
        float2 w3 = cmul(w1, w2), w5 = cmul(w1, w4), w6 = cmul(w2, w4);
        float2 w7 = cmul(w3, w4);
        va[1] = cmul(va[1], w1); va[2] = cmul(va[2], w2); va[3] = cmul(va[3], w3);
        va[4] = cmul(va[4], w4); va[5] = cmul(va[5], w5); va[6] = cmul(va[6], w6);
        va[7] = cmul(va[7], w7);
        dft8(va);
        vb[1] = cmul(vb[1], w1); vb[2] = cmul(vb[2], w2); vb[3] = cmul(vb[3], w3);
        vb[4] = cmul(vb[4], w4); vb[5] = cmul(vb[5], w5); vb[6] = cmul(vb[6], w6);
        vb[7] = cmul(vb[7], w7);
        dft8(vb);
        __syncthreads();   // all reads (both buffers) done before in-place writes
        const int d = ((t >> 3) << 6) + (t & 7);
        #pragma unroll
        for (int r = 0; r < 8; ++r) LA[sw(d + 8 * r)] = va[r];
        #pragma unroll
        for (int r = 0; r < 8; ++r) LB[sw(d + 8 * r)] = vb[r];
    }
    __syncthreads();

    // ---- stage 3: R=8, Ns=64 ----
    {
        #pragma unroll
        for (int r = 0; r < 8; ++r) va[r] = LA[sw(t + 256 * r)];
        #pragma unroll
        for (int r = 0; r < 8; ++r) vb[r] = LB[sw(t + 256 * r)];
        const float a = -(float)M_PI / 256.0f * (float)(t & 63);
        float2 w1 = sc(a), w2 = sc(2.0f * a), w4 = sc(4.0f * a);
        float2 w3 = cmul(w1, w2), w5 = cmul(w1, w4), w6 = cmul(w2, w4);
        float2 w7 = cmul(w3, w4);
        va[1] = cmul(va[1], w1); va[2] = cmul(va[2], w2); va[3] = cmul(va[3], w3);
        va[4] = cmul(va[4], w4); va[5] = cmul(va[5], w5); va[6] = cmul(va[6], w6);
        va[7] = cmul(va[7], w7);
        dft8(va);
        vb[1] = cmul(vb[1], w1); vb[2] = cmul(vb[2], w2); vb[3] = cmul(vb[3], w3);
        vb[4] = cmul(vb[4], w4); vb[5] = cmul(vb[5], w5); vb[6] = cmul(vb[6], w6);
        vb[7] = cmul(vb[7], w7);
        dft8(vb);
        __syncthreads();
        const int d = ((t >> 6) << 9) + (t & 63);
        #pragma unroll
        for (int r = 0; r < 8; ++r) LA[sw(d + 64 * r)] = va[r];
        #pragma unroll
        for (int r = 0; r < 8; ++r) LB[sw(d + 64 * r)] = vb[r];
    }
    __syncthreads();

    // ---- stage 4: R=4, Ns=512; in-place per thread (same indices), no barrier ----
    #pragma unroll
    for (int h = 0; h < 2; ++h) {
        const int j = t + 256 * h;
        const float a = -(float)M_PI / 1024.0f * (float)j;
        float2 w1 = sc(a), w2 = sc(2.0f * a);
        float2 w3 = cmul(w1, w2);
        float2 u[4];
        #pragma unroll
        for (int r = 0; r < 4; ++r) u[r] = LA[sw(j + 512 * r)];
        u[1] = cmul(u[1], w1); u[2] = cmul(u[2], w2); u[3] = cmul(u[3], w3);
        dft4(u);
        #pragma unroll
        for (int r = 0; r < 4; ++r) LA[sw(j + 512 * r)] = u[r];
        #pragma unroll
        for (int r = 0; r < 4; ++r) u[r] = LB[sw(j + 512 * r)];
        u[1] = cmul(u[1], w1); u[2] = cmul(u[2], w2); u[3] = cmul(u[3], w3);
        dft4(u);
        #pragma unroll
        for (int r = 0; r < 4; ++r) LB[sw(j + 512 * r)] = u[r];
    }
    __syncthreads();

    // ---- epilogue: rfft untangle + DCT twiddle (uu, ek shared across rows) ----
    const float2* __restrict__ ek = (const float2*)expk;
    float* __restrict__ dA = out + (size_t)rowA * NFULL;
    float* __restrict__ dB = out + (size_t)(rowA + 1) * NFULL;
    #pragma unroll
    for (int i = 0; i < 8; ++i) {
        const int k = t + T * i;
        if (k == 0) {
            float2 zA = LA[sw(0)];
            float2 zB = LB[sw(0)];
            float e0 = ek[0].x, eh = ek[NH].x;
            dA[0]  = e0 * (zA.x + zA.y);
            dA[NH] = eh * (zA.x - zA.y);
            dB[0]  = e0 * (zB.x + zB.y);
            dB[NH] = eh * (zB.x - zB.y);
        } else {
            float2 uu = sc(-(float)M_PI / 2048.0f * (float)k);
            float2 wk = ek[k];
            float2 wn = ek[NFULL - k];
            float2 Zk = LA[sw(k)];
            float2 Zr = LA[sw(NH - k)];
            float2 E = make_float2(0.5f * (Zk.x + Zr.x), 0.5f * (Zk.y - Zr.y));
            float2 O = make_float2(0.5f * (Zk.y + Zr.y), 0.5f * (Zr.x - Zk.x));
            float2 Y = make_float2(E.x + uu.x * O.x - uu.y * O.y,
                                   E.y + uu.x * O.y + uu.y * O.x);
            dA[k] = wk.x * Y.x - wk.y * Y.y;
            dA[NFULL - k] = wn.x * Y.x + wn.y * Y.y;
            Zk = LB[sw(k)];
            Zr = LB[sw(NH - k)];
            E = make_float2(0.5f * (Zk.x + Zr.x), 0.5f * (Zk.y - Zr.y));
            O = make_float2(0.5f * (Zk.y + Zr.y), 0.5f * (Zr.x - Zk.x));
            Y = make_float2(E.x + uu.x * O.x - uu.y * O.y,
                            E.y + uu.x * O.y + uu.y * O.x);
            dB[k] = wk.x * Y.x - wk.y * Y.y;
            dB[NFULL - k] = wn.x * Y.x + wn.y * Y.y;
        }
    }
}

// 32x32 LDS-tiled transpose
__global__ __launch_bounds__(256) void transpose4k(const float* __restrict__ in,
                                                   float* __restrict__ out) {
    __shared__ float tile[32][33];
    const int x0 = blockIdx.x * 32;
    const int y0 = blockIdx.y * 32;
    const int tx = threadIdx.x & 31;
    const int ty = threadIdx.x >> 5;

    #pragma unroll
    for (int i = 0; i < 32; i += 8)
        tile[ty + i][tx] = in[(size_t)(y0 + ty + i) * NFULL + (x0 + tx)];
    __syncthreads();
    #pragma unroll
    for (int i = 0; i < 32; i += 8)
        out[(size_t)(x0 + ty + i) * NFULL + (y0 + tx)] = tile[tx][ty + i];
}

extern "C" void kernel_launch(void* const* d_in, const int* in_sizes, int n_in,
                              void* d_out, int out_size, void* d_ws, size_t ws_size,
                              hipStream_t stream) {
    const float* x     = (const float*)d_in[0];
    const float* expkM = (const float*)d_in[1];
    const float* expkN = (const float*)d_in[2];
    float* out = (float*)d_out;
    float* ws1 = (float*)d_ws;

    dct_rows_rfft2<<<NFULL / 2, T, 0, stream>>>(x, expkN, ws1);
    transpose4k<<<dim3(128, 128), 256, 0, stream>>>(ws1, out);
    dct_rows_rfft2<<<NFULL / 2, T, 0, stream>>>(out, expkM, ws1);
    transpose4k<<<dim3(128, 128), 256, 0, stream>>>(ws1, out);
}